// Round 20
// baseline (200.050 us; speedup 1.0000x reference)
//
#include <hip/hip_runtime.h>
#include <math.h>

// Problem constants
#define NTOT 65536   // B*H*W = 64*32*32
#define KCB  1024
#define DIM  64

typedef float fvec2 __attribute__((ext_vector_type(2)));
typedef float fvec4 __attribute__((ext_vector_type(4)));
typedef short sh8  __attribute__((ext_vector_type(8)));   // 8 bf16 = 4 VGPRs

// d_out layout (floats), concatenated return order
static const size_t OFF_Q    = 0;          // [64,64,32,32] = 4194304
static const size_t OFF_LOSS = 4194304;    // scalar
static const size_t OFF_PERP = 4194305;    // scalar
static const size_t OFF_ENC  = 4194306;    // [65536,1024] = 67108864
static const size_t OFF_EMB  = 71303170;   // [1024,64]
static const size_t OFF_NCS  = 71368706;   // [1024]
static const size_t OFF_NEMA = 71369730;   // [1024,64]

// ws layout (bytes)
static const size_t WSO_IDX   = 0;         // int[65536]
static const size_t WSO_ESQ   = 262144;    // float[1024]
static const size_t WSO_LOSSP = 266240;    // float[4096]
static const size_t WSO_CNT   = 282624;    // int[1024]
static const size_t WSO_SCAL  = 286720;    // float[8] ([0]=n, [4]=done ctr)
static const size_t WSO_EBH   = 290816;    // ushort[65536] e_hi, B-frag-major
static const size_t WSO_EBL   = 421888;    // ushort[65536] e_lo
static const size_t WSO_ZC    = 4812800;   // float[65536*64] (optional compact z)
static const size_t WS_NEED_ZC = 4812800 + (size_t)NTOT * DIM * 4;

// bf16 round-to-nearest-even split helpers
__device__ __forceinline__ unsigned short f2bf(float f) {
    unsigned u = __builtin_bit_cast(unsigned, f);
    return (unsigned short)((u + 0x7FFFu + ((u >> 16) & 1u)) >> 16);
}
__device__ __forceinline__ float bf2f(unsigned short h) {
    unsigned u = ((unsigned)h) << 16;
    return __builtin_bit_cast(float, u);
}

// ---------------------------------------------------------------------------
// K0: split e into bf16 hi/lo (B-frag-major) + fused e_sq + (block 0)
// n = 0.99*sum(ecs) + 655.36 AND zero the tail's done-counter (runs before
// tail in stream order -> graph-replay-safe reset).
__global__ void k_eprep(const float* __restrict__ emb,
                        const float* __restrict__ ecs,
                        unsigned short* __restrict__ ebh,
                        unsigned short* __restrict__ ebl,
                        float* __restrict__ esq,
                        float* __restrict__ scal) {
    int gid = blockIdx.x * 256 + threadIdx.x;   // 32x256 = 8192
    int c = gid >> 3, ko8 = gid & 7;
    const fvec4* p = (const fvec4*)(emb + ((size_t)c << 6) + (ko8 << 3));
    fvec4 v0 = p[0], v1 = p[1];
    float f[8] = {v0.x, v0.y, v0.z, v0.w, v1.x, v1.y, v1.z, v1.w};
    sh8 h, l;
    float sq0 = 0.f, sq1 = 0.f;
#pragma unroll
    for (int j = 0; j < 8; ++j) {
        unsigned short hb = f2bf(f[j]);
        h[j] = (short)hb;
        l[j] = (short)f2bf(f[j] - bf2f(hb));
        if (j < 4) sq0 = fmaf(f[j], f[j], sq0); else sq1 = fmaf(f[j], f[j], sq1);
    }
    float sq = sq0 + sq1;
    sq += __shfl_xor(sq, 1, 64);
    sq += __shfl_xor(sq, 2, 64);
    sq += __shfl_xor(sq, 4, 64);
    if (ko8 == 0) esq[c] = sq;

    int ct = c >> 4, cl = c & 15, kc = ko8 >> 2, ko = ko8 & 3;
    size_t base = ((((size_t)ct << 1) + kc) << 9) + (((size_t)(ko << 4) + cl) << 3);
    *(sh8*)(ebh + base) = h;
    *(sh8*)(ebl + base) = l;

    if (blockIdx.x == 0) {
        __shared__ float sr[256];
        const int t = threadIdx.x;
        if (t == 0) ((int*)scal)[4] = 0;   // reset done-counter
        sr[t] = ecs[t] + ecs[t + 256] + ecs[t + 512] + ecs[t + 768];
        __syncthreads();
        for (int s = 128; s > 0; s >>= 1) {
            if (t < s) sr[t] += sr[t + s];
            __syncthreads();
        }
        if (t == 0) scal[0] = fmaf(0.99f, sr[0], 655.36f);
    }
}

// ---------------------------------------------------------------------------
// K1: assignment via MFMA (bf16x3 split) -> idx, loss partial, compact z.
// Round-18 version (r11 + esq staged in LDS). Plateaued at ~45-48us.
__global__ __launch_bounds__(256, 4)
void k_assign(const float* __restrict__ ze, const float* __restrict__ emb,
              const float* __restrict__ esq,
              const unsigned short* __restrict__ ebh,
              const unsigned short* __restrict__ ebl,
              int* __restrict__ idx_out, float* __restrict__ lossp,
              float* __restrict__ zc, int use_zc) {
    __shared__ float zt[4096];    // z tile [row][d] fp32
    __shared__ float etq[4096];   // merge arrays -> loss red
    __shared__ float esql[1024];  // esq staged (4 KB)
    __shared__ int   sfidx[64];

    const int tid  = threadIdx.x;
    const int blk  = blockIdx.x;
    const int b    = blk >> 4;
    const int hw0  = (blk & 15) << 6;
    const int n0   = blk << 6;
    const int lane = tid & 63;
    const int wave = tid >> 6;
    const int cg   = lane & 15;
    const int ko   = lane >> 4;

#pragma unroll
    for (int j = 0; j < 4; ++j) {
        int idx = tid + (j << 8);
        int d = idx >> 4, r0 = (idx & 15) << 2;
        const fvec4 v = *(const fvec4*)(ze + (((size_t)(b << 6) + d) << 10) + hw0 + r0);
        zt[(r0 + 0) * 64 + d] = v.x;
        zt[(r0 + 1) * 64 + d] = v.y;
        zt[(r0 + 2) * 64 + d] = v.z;
        zt[(r0 + 3) * 64 + d] = v.w;
    }
    {
        fvec4 e4 = *(const fvec4*)(esq + (tid << 2));
        *(fvec4*)&esql[tid << 2] = e4;
    }
    __syncthreads();

    const int arow = (wave << 4) + cg;
    sh8 Ah0, Ah1, Al0, Al1;
#pragma unroll
    for (int j = 0; j < 8; ++j) {
        float f0 = zt[arow * 64 + (ko << 3) + j];
        float f1 = zt[arow * 64 + 32 + (ko << 3) + j];
        unsigned short h0 = f2bf(f0), h1 = f2bf(f1);
        Ah0[j] = (short)h0;  Al0[j] = (short)f2bf(f0 - bf2f(h0));
        Ah1[j] = (short)h1;  Al1[j] = (short)f2bf(f1 - bf2f(h1));
    }

    float tb[4]  = {3.4e38f, 3.4e38f, 3.4e38f, 3.4e38f};
    float ts2[4] = {3.4e38f, 3.4e38f, 3.4e38f, 3.4e38f};
    int ti1[4] = {0, 0, 0, 0};
    int ti2[4] = {0, 0, 0, 0};

    const size_t lb = (size_t)lane << 3;
#define LOADB(d0, d1, d2, d3, ctv)                                  \
    { size_t o_ = ((size_t)(ctv) << 10) + lb;                       \
      d0 = *(const sh8*)(ebh + o_);                                 \
      d1 = *(const sh8*)(ebh + o_ + 512);                           \
      d2 = *(const sh8*)(ebl + o_);                                 \
      d3 = *(const sh8*)(ebl + o_ + 512); }

#define FOLD(ctv, acc)                                              \
    { const int code_ = ((ctv) << 4) + cg;                          \
      const float es_ = esql[code_];                                \
      _Pragma("unroll")                                             \
      for (int rg = 0; rg < 4; ++rg) {                              \
          float s_ = fmaf((acc)[rg], -2.0f, es_);                   \
          bool c1 = s_ < tb[rg];                                    \
          bool c2 = s_ < ts2[rg];                                   \
          ti2[rg] = c1 ? ti1[rg] : (c2 ? code_ : ti2[rg]);          \
          ts2[rg] = c1 ? tb[rg] : (c2 ? s_ : ts2[rg]);              \
          ti1[rg] = c1 ? code_ : ti1[rg];                           \
          tb[rg]  = c1 ? s_ : tb[rg];                               \
      } }

#define TILE(i) ((((i) + (blk << 1)) & 63))

    sh8 b0h0, b0h1, b0l0, b0l1, b1h0, b1h1, b1l0, b1l1;
    LOADB(b0h0, b0h1, b0l0, b0l1, TILE(0));
    LOADB(b1h0, b1h1, b1l0, b1l1, TILE(1));

    for (int i = 0; i < 64; i += 2) {
        fvec4 aa = {0.f, 0.f, 0.f, 0.f}, ab = {0.f, 0.f, 0.f, 0.f};
        aa = __builtin_amdgcn_mfma_f32_16x16x32_bf16(Ah0, b0h0, aa, 0, 0, 0);
        ab = __builtin_amdgcn_mfma_f32_16x16x32_bf16(Ah1, b0h1, ab, 0, 0, 0);
        aa = __builtin_amdgcn_mfma_f32_16x16x32_bf16(Ah0, b0l0, aa, 0, 0, 0);
        ab = __builtin_amdgcn_mfma_f32_16x16x32_bf16(Ah1, b0l1, ab, 0, 0, 0);
        aa = __builtin_amdgcn_mfma_f32_16x16x32_bf16(Al0, b0h0, aa, 0, 0, 0);
        ab = __builtin_amdgcn_mfma_f32_16x16x32_bf16(Al1, b0h1, ab, 0, 0, 0);
        const int ct0 = TILE(i);
        if (i + 2 < 64) LOADB(b0h0, b0h1, b0l0, b0l1, TILE(i + 2));
        fvec4 acc0 = aa + ab;
        FOLD(ct0, acc0);

        fvec4 ba = {0.f, 0.f, 0.f, 0.f}, bb = {0.f, 0.f, 0.f, 0.f};
        ba = __builtin_amdgcn_mfma_f32_16x16x32_bf16(Ah0, b1h0, ba, 0, 0, 0);
        bb = __builtin_amdgcn_mfma_f32_16x16x32_bf16(Ah1, b1h1, bb, 0, 0, 0);
        ba = __builtin_amdgcn_mfma_f32_16x16x32_bf16(Ah0, b1l0, ba, 0, 0, 0);
        bb = __builtin_amdgcn_mfma_f32_16x16x32_bf16(Ah1, b1l1, bb, 0, 0, 0);
        ba = __builtin_amdgcn_mfma_f32_16x16x32_bf16(Al0, b1h0, ba, 0, 0, 0);
        bb = __builtin_amdgcn_mfma_f32_16x16x32_bf16(Al1, b1h1, bb, 0, 0, 0);
        const int ct1 = TILE(i + 1);
        if (i + 3 < 64) LOADB(b1h0, b1h1, b1l0, b1l1, TILE(i + 3));
        fvec4 acc1 = ba + bb;
        FOLD(ct1, acc1);
    }
#undef TILE
#undef LOADB
#undef FOLD

    float* mb  = etq;
    float* ms2 = etq + 1024;
    int*   mi1 = (int*)(etq + 2048);
    int*   mi2 = (int*)(etq + 3072);
#pragma unroll
    for (int rg = 0; rg < 4; ++rg) {
        int row = (wave << 4) + (ko << 2) + rg;
        mb [(cg << 6) + row] = tb[rg];
        ms2[(cg << 6) + row] = ts2[rg];
        mi1[(cg << 6) + row] = ti1[rg];
        mi2[(cg << 6) + row] = ti2[rg];
    }
    __syncthreads();

    if (tid < 64) {
        const int r = tid;
        float fb = mb[r], fs2 = ms2[r];
        int fi1 = mi1[r], fi2 = mi2[r];
#pragma unroll
        for (int p = 1; p < 16; ++p) {
            float ob = mb[(p << 6) + r], os2 = ms2[(p << 6) + r];
            int oi1 = mi1[(p << 6) + r], oi2 = mi2[(p << 6) + r];
            if (ob < fb)       { fs2 = fb; fi2 = fi1; fb = ob; fi1 = oi1; }
            else if (ob < fs2) { fs2 = ob; fi2 = oi1; }
            if (os2 < fs2)     { fs2 = os2; fi2 = oi2; }
        }
        if (fs2 - fb < 2e-2f) {
            double d1 = 0.0, d2 = 0.0;
            const float* e1 = emb + (size_t)fi1 * 64;
            const float* e2 = emb + (size_t)fi2 * 64;
            for (int d = 0; d < 64; ++d) {
                double zd = (double)zt[r * 64 + d];
                double q1 = zd - (double)e1[d];
                double q2 = zd - (double)e2[d];
                d1 += q1 * q1;
                d2 += q2 * q2;
            }
            if ((d2 < d1) || (d2 == d1 && fi2 < fi1)) fi1 = fi2;
        }
        sfidx[r] = fi1;
        idx_out[n0 + r] = fi1;
    }
    __syncthreads();

    float lacc = 0.f;
    for (int i = tid; i < 1024; i += 256) {
        int r = i >> 4, d4 = (i & 15) << 2;
        const fvec4 zv = *(const fvec4*)&zt[(r << 6) + d4];
        const fvec4 ev = *(const fvec4*)(emb + ((size_t)sfidx[r] << 6) + d4);
        fvec4 df = ev - zv;
        lacc = fmaf(df.x, df.x, lacc);
        lacc = fmaf(df.y, df.y, lacc);
        lacc = fmaf(df.z, df.z, lacc);
        lacc = fmaf(df.w, df.w, lacc);
        if (use_zc)
            *(fvec4*)&zc[(((size_t)(n0 + r)) << 6) + d4] = zv;
    }
    __syncthreads();

    float* lred = etq;
    lred[tid] = lacc;
    __syncthreads();
    for (int s = 128; s > 0; s >>= 1) {
        if (tid < s) lred[tid] += lred[tid + s];
        __syncthreads();
    }
    if (tid == 0) lossp[blk] = lred[0];
}

// ---------------------------------------------------------------------------
// K2: merged tail. Odd blocks: output streaming. Even blocks: per-code
// full-scan stats + fused ncs/nema/embnorm. Round-20: scalars (loss +
// perplexity) fused via deterministic last-block pattern (done ctr in scal,
// zeroed by eprep) — k_scalars launch eliminated.
__global__ __launch_bounds__(256)
void k_tail(const int* __restrict__ idx, const float* __restrict__ zcmp,
            const float* __restrict__ ze, const float* __restrict__ emaw,
            const float* __restrict__ ecs, const float* __restrict__ emb,
            float* __restrict__ scal, const float* __restrict__ lossp,
            float* __restrict__ out, int* __restrict__ counts, int use_zc) {
    __shared__ __align__(16) char smem[17424];
    const int t = threadIdx.x;

    if (blockIdx.x & 1) {
        // ---------------- out role ----------------
        const int blk = blockIdx.x >> 1;
        const int b   = blk >> 4;
        const int hw0 = (blk & 15) << 6;
        const int n0  = blk << 6;
        int*   sfidx = (int*)smem;            // 64
        float* qt    = (float*)(smem + 256);  // 64*65

        if (t < 64) sfidx[t] = idx[n0 + t];
        __syncthreads();

        for (int i = t; i < 4096; i += 256) {
            int r = i >> 6, d = i & 63;
            qt[d * 65 + r] = emb[(size_t)sfidx[r] * 64 + d];
        }

        float* ebase = out + OFF_ENC;
        if (t < 255) {
            const int cb = 2 + (t << 2);
            for (int r = 0; r < 64; ++r) {
                const int fi = sfidx[r];
                fvec4 v;
                v.x = (fi == cb)     ? 1.0f : 0.0f;
                v.y = (fi == cb + 1) ? 1.0f : 0.0f;
                v.z = (fi == cb + 2) ? 1.0f : 0.0f;
                v.w = (fi == cb + 3) ? 1.0f : 0.0f;
                __builtin_nontemporal_store(
                    v, (fvec4*)(ebase + ((size_t)(n0 + r) << 10) + cb));
            }
        } else {
            for (int r = 0; r < 64; ++r) {
                const int fi = sfidx[r];
                float* rowp = ebase + ((size_t)(n0 + r) << 10);
                fvec2 hd, tl;
                hd.x = (fi == 0)    ? 1.0f : 0.0f;
                hd.y = (fi == 1)    ? 1.0f : 0.0f;
                tl.x = (fi == 1022) ? 1.0f : 0.0f;
                tl.y = (fi == 1023) ? 1.0f : 0.0f;
                __builtin_nontemporal_store(hd, (fvec2*)rowp);
                __builtin_nontemporal_store(tl, (fvec2*)(rowp + 1022));
            }
        }
        __syncthreads();

        for (int i = t; i < 4096; i += 256) {
            int d = i >> 6, r = i & 63;
            __builtin_nontemporal_store(
                qt[d * 65 + r],
                &out[OFF_Q + ((size_t)((b << 6) + d) << 10) + hw0 + r]);
        }
        return;
    }

    // ---------------- stats role (full scan) ----------------
    const int k    = blockIdx.x >> 1;
    const int g    = t >> 6;
    const int d    = t & 63;
    const int lane = t & 63;
    int*   s_list = (int*)smem;                    // 4096
    int*   s_wsum = (int*)(smem + 16384);          // 4
    float* s_red  = (float*)(smem + 16400);        // [4][64]

#define ZLOAD(n) (use_zc ? zcmp[((size_t)(n) << 6) + d] \
                         : ze[((((size_t)((n) >> 10) << 6) + d) << 10) + ((n) & 1023)])

    float a0 = 0.f, a1 = 0.f, a2 = 0.f, a3 = 0.f;
    int totalM = 0;

    for (int chunk = 0; chunk < 16; ++chunk) {
        const int base = chunk << 12;
        const int nb   = base + (t << 4);
        const int4* ip = (const int4*)(idx + nb);
        const int4 v0 = ip[0], v1 = ip[1], v2 = ip[2], v3 = ip[3];

        int c = 0;
        c += (v0.x == k) + (v0.y == k) + (v0.z == k) + (v0.w == k);
        c += (v1.x == k) + (v1.y == k) + (v1.z == k) + (v1.w == k);
        c += (v2.x == k) + (v2.y == k) + (v2.z == k) + (v2.w == k);
        c += (v3.x == k) + (v3.y == k) + (v3.z == k) + (v3.w == k);

        int inc = c;
#pragma unroll
        for (int off = 1; off < 64; off <<= 1) {
            int y = __shfl_up(inc, (unsigned)off, 64);
            if (lane >= off) inc += y;
        }
        if (lane == 63) s_wsum[g] = inc;
        __syncthreads();                            // (A)

        int wbase = 0;
#pragma unroll
        for (int w = 0; w < 4; ++w) wbase += (w < g) ? s_wsum[w] : 0;
        const int M = s_wsum[0] + s_wsum[1] + s_wsum[2] + s_wsum[3];
        int pos = wbase + inc - c;

        if (v0.x == k) s_list[pos++] = nb + 0;
        if (v0.y == k) s_list[pos++] = nb + 1;
        if (v0.z == k) s_list[pos++] = nb + 2;
        if (v0.w == k) s_list[pos++] = nb + 3;
        if (v1.x == k) s_list[pos++] = nb + 4;
        if (v1.y == k) s_list[pos++] = nb + 5;
        if (v1.z == k) s_list[pos++] = nb + 6;
        if (v1.w == k) s_list[pos++] = nb + 7;
        if (v2.x == k) s_list[pos++] = nb + 8;
        if (v2.y == k) s_list[pos++] = nb + 9;
        if (v2.z == k) s_list[pos++] = nb + 10;
        if (v2.w == k) s_list[pos++] = nb + 11;
        if (v3.x == k) s_list[pos++] = nb + 12;
        if (v3.y == k) s_list[pos++] = nb + 13;
        if (v3.z == k) s_list[pos++] = nb + 14;
        if (v3.w == k) s_list[pos++] = nb + 15;
        __syncthreads();                            // (B)

        int j = g;
        for (; j + 12 < M; j += 16) {
            int n0_ = s_list[j], n1_ = s_list[j + 4];
            int n2_ = s_list[j + 8], n3_ = s_list[j + 12];
            float z0 = ZLOAD(n0_), z1 = ZLOAD(n1_);
            float z2 = ZLOAD(n2_), z3 = ZLOAD(n3_);
            a0 += z0; a1 += z1; a2 += z2; a3 += z3;
        }
        for (; j < M; j += 4) a0 += ZLOAD(s_list[j]);
        totalM += M;
        __syncthreads();                            // (C)
    }
#undef ZLOAD

    s_red[(g << 6) + d] = (a0 + a1) + (a2 + a3);
    __syncthreads();
    if (g == 0) {
        float s = ((s_red[d] + s_red[64 + d]) + s_red[128 + d]) + s_red[192 + d];
        float nema = fmaf(0.01f, s, 0.99f * emaw[((size_t)k << 6) + d]);
        out[OFF_NEMA + ((size_t)k << 6) + d] = nema;
        float n   = scal[0];
        float ncs = fmaf(0.01f, (float)totalM, 0.99f * ecs[k]);
        float cs  = (ncs + 1e-10f) / (n + 1.024e-7f) * n;
        out[OFF_EMB + ((size_t)k << 6) + d] = nema / cs;
    }
    if (t == 0) {
        counts[k] = totalM;
        out[OFF_NCS + k] = fmaf(0.01f, (float)totalM, 0.99f * ecs[k]);
    }

    // ---- last-block scalars: loss + perplexity (deterministic values) ----
    __shared__ int isLast;
    if (t == 0) {
        __threadfence();
        int old = atomicAdd((int*)scal + 4, 1);
        isLast = (old == 1023);
    }
    __syncthreads();
    if (isLast) {
        float* sr = (float*)smem;   // s_list dead
        float v = lossp[t] + lossp[t + 256] + lossp[t + 512] + lossp[t + 768];
        sr[t] = v;
        __syncthreads();
        for (int s = 128; s > 0; s >>= 1) {
            if (t < s) sr[t] += sr[t + s];
            __syncthreads();
        }
        if (t == 0) out[OFF_LOSS] = sr[0] * (0.25f / 4194304.0f);
        __syncthreads();

        float pv = 0.f;
        for (int i = t; i < 1024; i += 256) {
            float p = (float)counts[i] * (1.0f / 65536.0f);
            pv += p * logf(p + 1e-10f);
        }
        sr[t] = pv;
        __syncthreads();
        for (int s = 128; s > 0; s >>= 1) {
            if (t < s) sr[t] += sr[t + s];
            __syncthreads();
        }
        if (t == 0) out[OFF_PERP] = expf(-sr[0]);
    }
}

// ---------------------------------------------------------------------------
extern "C" void kernel_launch(void* const* d_in, const int* in_sizes, int n_in,
                              void* d_out, int out_size, void* d_ws, size_t ws_size,
                              hipStream_t stream) {
    const float* ze   = (const float*)d_in[0];
    const float* emb  = (const float*)d_in[1];
    const float* ecs  = (const float*)d_in[2];
    const float* emaw = (const float*)d_in[3];
    float* out = (float*)d_out;
    char*  ws  = (char*)d_ws;

    int*            idx    = (int*)(ws + WSO_IDX);
    float*          esq    = (float*)(ws + WSO_ESQ);
    float*          lossp  = (float*)(ws + WSO_LOSSP);
    int*            counts = (int*)(ws + WSO_CNT);
    float*          scal   = (float*)(ws + WSO_SCAL);
    unsigned short* ebh    = (unsigned short*)(ws + WSO_EBH);
    unsigned short* ebl    = (unsigned short*)(ws + WSO_EBL);
    float*          zc     = (float*)(ws + WSO_ZC);
    const int use_zc = (ws_size >= WS_NEED_ZC) ? 1 : 0;

    k_eprep  <<<32,   256, 0, stream>>>(emb, ecs, ebh, ebl, esq, scal);
    k_assign <<<1024, 256, 0, stream>>>(ze, emb, esq, ebh, ebl, idx, lossp, zc, use_zc);
    k_tail   <<<2048, 256, 0, stream>>>(idx, zc, ze, emaw, ecs, emb, scal, lossp, out, counts, use_zc);
}

// Round 21
// 147.840 us; speedup vs baseline: 1.3531x; 1.3531x over previous
//
#include <hip/hip_runtime.h>
#include <math.h>

// Problem constants
#define NTOT 65536   // B*H*W = 64*32*32
#define KCB  1024
#define DIM  64

typedef float fvec2 __attribute__((ext_vector_type(2)));
typedef float fvec4 __attribute__((ext_vector_type(4)));
typedef short sh8  __attribute__((ext_vector_type(8)));   // 8 bf16 = 4 VGPRs

// d_out layout (floats), concatenated return order
static const size_t OFF_Q    = 0;          // [64,64,32,32] = 4194304
static const size_t OFF_LOSS = 4194304;    // scalar
static const size_t OFF_PERP = 4194305;    // scalar
static const size_t OFF_ENC  = 4194306;    // [65536,1024] = 67108864
static const size_t OFF_EMB  = 71303170;   // [1024,64]
static const size_t OFF_NCS  = 71368706;   // [1024]
static const size_t OFF_NEMA = 71369730;   // [1024,64]

// ws layout (bytes)
static const size_t WSO_IDX   = 0;         // int[65536]
static const size_t WSO_ESQ   = 262144;    // float[1024]
static const size_t WSO_LOSSP = 266240;    // float[4096]
static const size_t WSO_CNT   = 282624;    // int[1024]
static const size_t WSO_SCAL  = 286720;    // float[8]
static const size_t WSO_EBH   = 290816;    // ushort[65536] e_hi, B-frag-major
static const size_t WSO_EBL   = 421888;    // ushort[65536] e_lo
static const size_t WSO_ZC    = 4812800;   // float[65536*64] (optional compact z)
static const size_t WS_NEED_ZC = 4812800 + (size_t)NTOT * DIM * 4;

// bf16 round-to-nearest-even split helpers
__device__ __forceinline__ unsigned short f2bf(float f) {
    unsigned u = __builtin_bit_cast(unsigned, f);
    return (unsigned short)((u + 0x7FFFu + ((u >> 16) & 1u)) >> 16);
}
__device__ __forceinline__ float bf2f(unsigned short h) {
    unsigned u = ((unsigned)h) << 16;
    return __builtin_bit_cast(float, u);
}

// ---------------------------------------------------------------------------
// K0: split e into bf16 hi/lo (B-frag-major) + fused e_sq + (block 0)
// n = 0.99*sum(ecs) + 655.36 (precomputed from the INPUT so the stats
// role can fuse embnorm).
__global__ void k_eprep(const float* __restrict__ emb,
                        const float* __restrict__ ecs,
                        unsigned short* __restrict__ ebh,
                        unsigned short* __restrict__ ebl,
                        float* __restrict__ esq,
                        float* __restrict__ scal) {
    int gid = blockIdx.x * 256 + threadIdx.x;   // 32x256 = 8192
    int c = gid >> 3, ko8 = gid & 7;
    const fvec4* p = (const fvec4*)(emb + ((size_t)c << 6) + (ko8 << 3));
    fvec4 v0 = p[0], v1 = p[1];
    float f[8] = {v0.x, v0.y, v0.z, v0.w, v1.x, v1.y, v1.z, v1.w};
    sh8 h, l;
    float sq0 = 0.f, sq1 = 0.f;
#pragma unroll
    for (int j = 0; j < 8; ++j) {
        unsigned short hb = f2bf(f[j]);
        h[j] = (short)hb;
        l[j] = (short)f2bf(f[j] - bf2f(hb));
        if (j < 4) sq0 = fmaf(f[j], f[j], sq0); else sq1 = fmaf(f[j], f[j], sq1);
    }
    float sq = sq0 + sq1;
    sq += __shfl_xor(sq, 1, 64);
    sq += __shfl_xor(sq, 2, 64);
    sq += __shfl_xor(sq, 4, 64);
    if (ko8 == 0) esq[c] = sq;

    int ct = c >> 4, cl = c & 15, kc = ko8 >> 2, ko = ko8 & 3;
    size_t base = ((((size_t)ct << 1) + kc) << 9) + (((size_t)(ko << 4) + cl) << 3);
    *(sh8*)(ebh + base) = h;
    *(sh8*)(ebl + base) = l;

    // block 0: n = 0.99*sum(ecs) + 655.36 (deterministic tree)
    if (blockIdx.x == 0) {
        __shared__ float sr[256];
        const int t = threadIdx.x;
        sr[t] = ecs[t] + ecs[t + 256] + ecs[t + 512] + ecs[t + 768];
        __syncthreads();
        for (int s = 128; s > 0; s >>= 1) {
            if (t < s) sr[t] += sr[t + s];
            __syncthreads();
        }
        if (t == 0) scal[0] = fmaf(0.99f, sr[0], 655.36f);
    }
}

// ---------------------------------------------------------------------------
// K1: assignment via MFMA (bf16x3 split) -> idx, loss partial, compact z.
// Round-18 version (r11 + esq staged in LDS). Plateaued at ~45-48us.
__global__ __launch_bounds__(256, 4)
void k_assign(const float* __restrict__ ze, const float* __restrict__ emb,
              const float* __restrict__ esq,
              const unsigned short* __restrict__ ebh,
              const unsigned short* __restrict__ ebl,
              int* __restrict__ idx_out, float* __restrict__ lossp,
              float* __restrict__ zc, int use_zc) {
    __shared__ float zt[4096];    // z tile [row][d] fp32
    __shared__ float etq[4096];   // merge arrays -> loss red
    __shared__ float esql[1024];  // esq staged (4 KB)
    __shared__ int   sfidx[64];

    const int tid  = threadIdx.x;
    const int blk  = blockIdx.x;
    const int b    = blk >> 4;
    const int hw0  = (blk & 15) << 6;
    const int n0   = blk << 6;
    const int lane = tid & 63;
    const int wave = tid >> 6;
    const int cg   = lane & 15;
    const int ko   = lane >> 4;

#pragma unroll
    for (int j = 0; j < 4; ++j) {
        int idx = tid + (j << 8);
        int d = idx >> 4, r0 = (idx & 15) << 2;
        const fvec4 v = *(const fvec4*)(ze + (((size_t)(b << 6) + d) << 10) + hw0 + r0);
        zt[(r0 + 0) * 64 + d] = v.x;
        zt[(r0 + 1) * 64 + d] = v.y;
        zt[(r0 + 2) * 64 + d] = v.z;
        zt[(r0 + 3) * 64 + d] = v.w;
    }
    {
        fvec4 e4 = *(const fvec4*)(esq + (tid << 2));
        *(fvec4*)&esql[tid << 2] = e4;
    }
    __syncthreads();

    const int arow = (wave << 4) + cg;
    sh8 Ah0, Ah1, Al0, Al1;
#pragma unroll
    for (int j = 0; j < 8; ++j) {
        float f0 = zt[arow * 64 + (ko << 3) + j];
        float f1 = zt[arow * 64 + 32 + (ko << 3) + j];
        unsigned short h0 = f2bf(f0), h1 = f2bf(f1);
        Ah0[j] = (short)h0;  Al0[j] = (short)f2bf(f0 - bf2f(h0));
        Ah1[j] = (short)h1;  Al1[j] = (short)f2bf(f1 - bf2f(h1));
    }

    float tb[4]  = {3.4e38f, 3.4e38f, 3.4e38f, 3.4e38f};
    float ts2[4] = {3.4e38f, 3.4e38f, 3.4e38f, 3.4e38f};
    int ti1[4] = {0, 0, 0, 0};
    int ti2[4] = {0, 0, 0, 0};

    const size_t lb = (size_t)lane << 3;
#define LOADB(d0, d1, d2, d3, ctv)                                  \
    { size_t o_ = ((size_t)(ctv) << 10) + lb;                       \
      d0 = *(const sh8*)(ebh + o_);                                 \
      d1 = *(const sh8*)(ebh + o_ + 512);                           \
      d2 = *(const sh8*)(ebl + o_);                                 \
      d3 = *(const sh8*)(ebl + o_ + 512); }

#define FOLD(ctv, acc)                                              \
    { const int code_ = ((ctv) << 4) + cg;                          \
      const float es_ = esql[code_];                                \
      _Pragma("unroll")                                             \
      for (int rg = 0; rg < 4; ++rg) {                              \
          float s_ = fmaf((acc)[rg], -2.0f, es_);                   \
          bool c1 = s_ < tb[rg];                                    \
          bool c2 = s_ < ts2[rg];                                   \
          ti2[rg] = c1 ? ti1[rg] : (c2 ? code_ : ti2[rg]);          \
          ts2[rg] = c1 ? tb[rg] : (c2 ? s_ : ts2[rg]);              \
          ti1[rg] = c1 ? code_ : ti1[rg];                           \
          tb[rg]  = c1 ? s_ : tb[rg];                               \
      } }

#define TILE(i) ((((i) + (blk << 1)) & 63))

    sh8 b0h0, b0h1, b0l0, b0l1, b1h0, b1h1, b1l0, b1l1;
    LOADB(b0h0, b0h1, b0l0, b0l1, TILE(0));
    LOADB(b1h0, b1h1, b1l0, b1l1, TILE(1));

    for (int i = 0; i < 64; i += 2) {
        fvec4 aa = {0.f, 0.f, 0.f, 0.f}, ab = {0.f, 0.f, 0.f, 0.f};
        aa = __builtin_amdgcn_mfma_f32_16x16x32_bf16(Ah0, b0h0, aa, 0, 0, 0);
        ab = __builtin_amdgcn_mfma_f32_16x16x32_bf16(Ah1, b0h1, ab, 0, 0, 0);
        aa = __builtin_amdgcn_mfma_f32_16x16x32_bf16(Ah0, b0l0, aa, 0, 0, 0);
        ab = __builtin_amdgcn_mfma_f32_16x16x32_bf16(Ah1, b0l1, ab, 0, 0, 0);
        aa = __builtin_amdgcn_mfma_f32_16x16x32_bf16(Al0, b0h0, aa, 0, 0, 0);
        ab = __builtin_amdgcn_mfma_f32_16x16x32_bf16(Al1, b0h1, ab, 0, 0, 0);
        const int ct0 = TILE(i);
        if (i + 2 < 64) LOADB(b0h0, b0h1, b0l0, b0l1, TILE(i + 2));
        fvec4 acc0 = aa + ab;
        FOLD(ct0, acc0);

        fvec4 ba = {0.f, 0.f, 0.f, 0.f}, bb = {0.f, 0.f, 0.f, 0.f};
        ba = __builtin_amdgcn_mfma_f32_16x16x32_bf16(Ah0, b1h0, ba, 0, 0, 0);
        bb = __builtin_amdgcn_mfma_f32_16x16x32_bf16(Ah1, b1h1, bb, 0, 0, 0);
        ba = __builtin_amdgcn_mfma_f32_16x16x32_bf16(Ah0, b1l0, ba, 0, 0, 0);
        bb = __builtin_amdgcn_mfma_f32_16x16x32_bf16(Ah1, b1l1, bb, 0, 0, 0);
        ba = __builtin_amdgcn_mfma_f32_16x16x32_bf16(Al0, b1h0, ba, 0, 0, 0);
        bb = __builtin_amdgcn_mfma_f32_16x16x32_bf16(Al1, b1h1, bb, 0, 0, 0);
        const int ct1 = TILE(i + 1);
        if (i + 3 < 64) LOADB(b1h0, b1h1, b1l0, b1l1, TILE(i + 3));
        fvec4 acc1 = ba + bb;
        FOLD(ct1, acc1);
    }
#undef TILE
#undef LOADB
#undef FOLD

    float* mb  = etq;
    float* ms2 = etq + 1024;
    int*   mi1 = (int*)(etq + 2048);
    int*   mi2 = (int*)(etq + 3072);
#pragma unroll
    for (int rg = 0; rg < 4; ++rg) {
        int row = (wave << 4) + (ko << 2) + rg;
        mb [(cg << 6) + row] = tb[rg];
        ms2[(cg << 6) + row] = ts2[rg];
        mi1[(cg << 6) + row] = ti1[rg];
        mi2[(cg << 6) + row] = ti2[rg];
    }
    __syncthreads();

    if (tid < 64) {
        const int r = tid;
        float fb = mb[r], fs2 = ms2[r];
        int fi1 = mi1[r], fi2 = mi2[r];
#pragma unroll
        for (int p = 1; p < 16; ++p) {
            float ob = mb[(p << 6) + r], os2 = ms2[(p << 6) + r];
            int oi1 = mi1[(p << 6) + r], oi2 = mi2[(p << 6) + r];
            if (ob < fb)       { fs2 = fb; fi2 = fi1; fb = ob; fi1 = oi1; }
            else if (ob < fs2) { fs2 = ob; fi2 = oi1; }
            if (os2 < fs2)     { fs2 = os2; fi2 = oi2; }
        }
        if (fs2 - fb < 2e-2f) {
            double d1 = 0.0, d2 = 0.0;
            const float* e1 = emb + (size_t)fi1 * 64;
            const float* e2 = emb + (size_t)fi2 * 64;
            for (int d = 0; d < 64; ++d) {
                double zd = (double)zt[r * 64 + d];
                double q1 = zd - (double)e1[d];
                double q2 = zd - (double)e2[d];
                d1 += q1 * q1;
                d2 += q2 * q2;
            }
            if ((d2 < d1) || (d2 == d1 && fi2 < fi1)) fi1 = fi2;
        }
        sfidx[r] = fi1;
        idx_out[n0 + r] = fi1;
    }
    __syncthreads();

    float lacc = 0.f;
    for (int i = tid; i < 1024; i += 256) {
        int r = i >> 4, d4 = (i & 15) << 2;
        const fvec4 zv = *(const fvec4*)&zt[(r << 6) + d4];
        const fvec4 ev = *(const fvec4*)(emb + ((size_t)sfidx[r] << 6) + d4);
        fvec4 df = ev - zv;
        lacc = fmaf(df.x, df.x, lacc);
        lacc = fmaf(df.y, df.y, lacc);
        lacc = fmaf(df.z, df.z, lacc);
        lacc = fmaf(df.w, df.w, lacc);
        if (use_zc)
            *(fvec4*)&zc[(((size_t)(n0 + r)) << 6) + d4] = zv;
    }
    __syncthreads();

    float* lred = etq;
    lred[tid] = lacc;
    __syncthreads();
    for (int s = 128; s > 0; s >>= 1) {
        if (tid < s) lred[tid] += lred[tid + s];
        __syncthreads();
    }
    if (tid == 0) lossp[blk] = lred[0];
}

// ---------------------------------------------------------------------------
// K2: merged tail. Odd blocks: output streaming. Even blocks: per-code
// full-scan stats + fused ncs/nema/embnorm. (r19 version — NO fence/atomic;
// r20's last-block fusion regressed +51us: device-scope fences poison the
// co-resident write streams.)
__global__ __launch_bounds__(256)
void k_tail(const int* __restrict__ idx, const float* __restrict__ zcmp,
            const float* __restrict__ ze, const float* __restrict__ emaw,
            const float* __restrict__ ecs, const float* __restrict__ emb,
            const float* __restrict__ scal,
            float* __restrict__ out, int* __restrict__ counts, int use_zc) {
    __shared__ __align__(16) char smem[17424];
    const int t = threadIdx.x;

    if (blockIdx.x & 1) {
        // ---------------- out role ----------------
        const int blk = blockIdx.x >> 1;
        const int b   = blk >> 4;
        const int hw0 = (blk & 15) << 6;
        const int n0  = blk << 6;
        int*   sfidx = (int*)smem;            // 64
        float* qt    = (float*)(smem + 256);  // 64*65

        if (t < 64) sfidx[t] = idx[n0 + t];
        __syncthreads();

        for (int i = t; i < 4096; i += 256) {
            int r = i >> 6, d = i & 63;
            qt[d * 65 + r] = emb[(size_t)sfidx[r] * 64 + d];
        }

        float* ebase = out + OFF_ENC;
        if (t < 255) {
            const int cb = 2 + (t << 2);
            for (int r = 0; r < 64; ++r) {
                const int fi = sfidx[r];
                fvec4 v;
                v.x = (fi == cb)     ? 1.0f : 0.0f;
                v.y = (fi == cb + 1) ? 1.0f : 0.0f;
                v.z = (fi == cb + 2) ? 1.0f : 0.0f;
                v.w = (fi == cb + 3) ? 1.0f : 0.0f;
                __builtin_nontemporal_store(
                    v, (fvec4*)(ebase + ((size_t)(n0 + r) << 10) + cb));
            }
        } else {
            for (int r = 0; r < 64; ++r) {
                const int fi = sfidx[r];
                float* rowp = ebase + ((size_t)(n0 + r) << 10);
                fvec2 hd, tl;
                hd.x = (fi == 0)    ? 1.0f : 0.0f;
                hd.y = (fi == 1)    ? 1.0f : 0.0f;
                tl.x = (fi == 1022) ? 1.0f : 0.0f;
                tl.y = (fi == 1023) ? 1.0f : 0.0f;
                __builtin_nontemporal_store(hd, (fvec2*)rowp);
                __builtin_nontemporal_store(tl, (fvec2*)(rowp + 1022));
            }
        }
        __syncthreads();

        for (int i = t; i < 4096; i += 256) {
            int d = i >> 6, r = i & 63;
            __builtin_nontemporal_store(
                qt[d * 65 + r],
                &out[OFF_Q + ((size_t)((b << 6) + d) << 10) + hw0 + r]);
        }
        return;
    }

    // ---------------- stats role (full scan) ----------------
    const int k    = blockIdx.x >> 1;
    const int g    = t >> 6;
    const int d    = t & 63;
    const int lane = t & 63;
    int*   s_list = (int*)smem;                    // 4096
    int*   s_wsum = (int*)(smem + 16384);          // 4
    float* s_red  = (float*)(smem + 16400);        // [4][64]

#define ZLOAD(n) (use_zc ? zcmp[((size_t)(n) << 6) + d] \
                         : ze[((((size_t)((n) >> 10) << 6) + d) << 10) + ((n) & 1023)])

    float a0 = 0.f, a1 = 0.f, a2 = 0.f, a3 = 0.f;
    int totalM = 0;

    for (int chunk = 0; chunk < 16; ++chunk) {
        const int base = chunk << 12;
        const int nb   = base + (t << 4);
        const int4* ip = (const int4*)(idx + nb);
        const int4 v0 = ip[0], v1 = ip[1], v2 = ip[2], v3 = ip[3];

        int c = 0;
        c += (v0.x == k) + (v0.y == k) + (v0.z == k) + (v0.w == k);
        c += (v1.x == k) + (v1.y == k) + (v1.z == k) + (v1.w == k);
        c += (v2.x == k) + (v2.y == k) + (v2.z == k) + (v2.w == k);
        c += (v3.x == k) + (v3.y == k) + (v3.z == k) + (v3.w == k);

        int inc = c;
#pragma unroll
        for (int off = 1; off < 64; off <<= 1) {
            int y = __shfl_up(inc, (unsigned)off, 64);
            if (lane >= off) inc += y;
        }
        if (lane == 63) s_wsum[g] = inc;
        __syncthreads();                            // (A)

        int wbase = 0;
#pragma unroll
        for (int w = 0; w < 4; ++w) wbase += (w < g) ? s_wsum[w] : 0;
        const int M = s_wsum[0] + s_wsum[1] + s_wsum[2] + s_wsum[3];
        int pos = wbase + inc - c;

        if (v0.x == k) s_list[pos++] = nb + 0;
        if (v0.y == k) s_list[pos++] = nb + 1;
        if (v0.z == k) s_list[pos++] = nb + 2;
        if (v0.w == k) s_list[pos++] = nb + 3;
        if (v1.x == k) s_list[pos++] = nb + 4;
        if (v1.y == k) s_list[pos++] = nb + 5;
        if (v1.z == k) s_list[pos++] = nb + 6;
        if (v1.w == k) s_list[pos++] = nb + 7;
        if (v2.x == k) s_list[pos++] = nb + 8;
        if (v2.y == k) s_list[pos++] = nb + 9;
        if (v2.z == k) s_list[pos++] = nb + 10;
        if (v2.w == k) s_list[pos++] = nb + 11;
        if (v3.x == k) s_list[pos++] = nb + 12;
        if (v3.y == k) s_list[pos++] = nb + 13;
        if (v3.z == k) s_list[pos++] = nb + 14;
        if (v3.w == k) s_list[pos++] = nb + 15;
        __syncthreads();                            // (B)

        int j = g;
        for (; j + 12 < M; j += 16) {
            int n0_ = s_list[j], n1_ = s_list[j + 4];
            int n2_ = s_list[j + 8], n3_ = s_list[j + 12];
            float z0 = ZLOAD(n0_), z1 = ZLOAD(n1_);
            float z2 = ZLOAD(n2_), z3 = ZLOAD(n3_);
            a0 += z0; a1 += z1; a2 += z2; a3 += z3;
        }
        for (; j < M; j += 4) a0 += ZLOAD(s_list[j]);
        totalM += M;
        __syncthreads();                            // (C)
    }
#undef ZLOAD

    s_red[(g << 6) + d] = (a0 + a1) + (a2 + a3);
    __syncthreads();
    if (g == 0) {
        float s = ((s_red[d] + s_red[64 + d]) + s_red[128 + d]) + s_red[192 + d];
        float nema = fmaf(0.01f, s, 0.99f * emaw[((size_t)k << 6) + d]);
        out[OFF_NEMA + ((size_t)k << 6) + d] = nema;
        float n   = scal[0];
        float ncs = fmaf(0.01f, (float)totalM, 0.99f * ecs[k]);
        float cs  = (ncs + 1e-10f) / (n + 1.024e-7f) * n;
        out[OFF_EMB + ((size_t)k << 6) + d] = nema / cs;
    }
    if (t == 0) {
        counts[k] = totalM;
        out[OFF_NCS + k] = fmaf(0.01f, (float)totalM, 0.99f * ecs[k]);
    }
}

// ---------------------------------------------------------------------------
// K4: scalars — loss + perplexity
__global__ void k_scalars(const float* __restrict__ lossp, const int* __restrict__ counts,
                          float* __restrict__ out) {
    __shared__ float sr[256];
    const int t = threadIdx.x;

    float v = lossp[t] + lossp[t + 256] + lossp[t + 512] + lossp[t + 768];
    sr[t] = v;
    __syncthreads();
    for (int s = 128; s > 0; s >>= 1) { if (t < s) sr[t] += sr[t + s]; __syncthreads(); }
    if (t == 0) out[OFF_LOSS] = sr[0] * (0.25f / 4194304.0f);
    __syncthreads();

    float pv = 0.f;
    for (int i = t; i < 1024; i += 256) {
        float p = (float)counts[i] * (1.0f / 65536.0f);
        pv += p * logf(p + 1e-10f);
    }
    sr[t] = pv;
    __syncthreads();
    for (int s = 128; s > 0; s >>= 1) { if (t < s) sr[t] += sr[t + s]; __syncthreads(); }
    if (t == 0) out[OFF_PERP] = expf(-sr[0]);
}

// ---------------------------------------------------------------------------
extern "C" void kernel_launch(void* const* d_in, const int* in_sizes, int n_in,
                              void* d_out, int out_size, void* d_ws, size_t ws_size,
                              hipStream_t stream) {
    const float* ze   = (const float*)d_in[0];
    const float* emb  = (const float*)d_in[1];
    const float* ecs  = (const float*)d_in[2];
    const float* emaw = (const float*)d_in[3];
    float* out = (float*)d_out;
    char*  ws  = (char*)d_ws;

    int*            idx    = (int*)(ws + WSO_IDX);
    float*          esq    = (float*)(ws + WSO_ESQ);
    float*          lossp  = (float*)(ws + WSO_LOSSP);
    int*            counts = (int*)(ws + WSO_CNT);
    float*          scal   = (float*)(ws + WSO_SCAL);
    unsigned short* ebh    = (unsigned short*)(ws + WSO_EBH);
    unsigned short* ebl    = (unsigned short*)(ws + WSO_EBL);
    float*          zc     = (float*)(ws + WSO_ZC);
    const int use_zc = (ws_size >= WS_NEED_ZC) ? 1 : 0;

    k_eprep  <<<32,   256, 0, stream>>>(emb, ecs, ebh, ebl, esq, scal);
    k_assign <<<1024, 256, 0, stream>>>(ze, emb, esq, ebh, ebl, idx, lossp, zc, use_zc);
    k_tail   <<<2048, 256, 0, stream>>>(idx, zc, ze, emaw, ecs, emb, scal, out, counts, use_zc);
    k_scalars<<<1,    256, 0, stream>>>(lossp, counts, out);
}